// Round 1
// baseline (729.582 us; speedup 1.0000x reference)
//
#include <hip/hip_runtime.h>

#define BSZ   128
#define CC    2048
#define HW    196
#define NDESC 32
#define NANS  1845

// ---------------------------------------------------------------------------
// Kernel 0: group batch indices by instance id. 1 block, 128 threads.
// ---------------------------------------------------------------------------
__global__ void group_kernel(const int* __restrict__ inst,
                             int* __restrict__ counts,
                             int* __restrict__ lists) {
    int t = threadIdx.x;
    if (t < NDESC) counts[t] = 0;
    __syncthreads();
    int i = inst[t];                      // 0..31
    int slot = atomicAdd(&counts[i], 1);
    lists[i * BSZ + slot] = t;
}

// ---------------------------------------------------------------------------
// Kernel 1: attended[b][c] = (1/196) * sum_hw mask[b][hw] * feat[b][c][hw]
// One wave (64 lanes) per (b,c) row; 49 float4 loads cover 196 floats.
// ---------------------------------------------------------------------------
__global__ __launch_bounds__(256) void attend_kernel(
        const float* __restrict__ mask,
        const float* __restrict__ feat,
        float* __restrict__ attended) {
    int row  = blockIdx.x * 4 + (threadIdx.x >> 6);   // row = b*CC + c
    int lane = threadIdx.x & 63;
    int b    = row >> 11;                             // CC = 2048

    const float* frow = feat + (size_t)row * HW;
    const float* mrow = mask + (size_t)b * HW;

    float partial = 0.f;
    if (lane < 49) {
        float4 f = *(const float4*)(frow + lane * 4);
        float4 m = *(const float4*)(mrow + lane * 4);
        partial = f.x * m.x + f.y * m.y + f.z * m.z + f.w * m.w;
    }
    #pragma unroll
    for (int off = 32; off; off >>= 1)
        partial += __shfl_xor(partial, off, 64);

    if (lane == 0) attended[row] = partial * (1.f / 196.f);
}

// ---------------------------------------------------------------------------
// Kernel 2: grouped GEMM. Grid = NDESC * ceil(NANS/8). 4 waves/block,
// each wave holds 2 W rows in registers and loops over the group's
// attended vectors (L2-resident, 1 MB total). W is read exactly once.
// ---------------------------------------------------------------------------
#define ATILES ((NANS + 7) / 8)   // 231

__global__ __launch_bounds__(256) void gemm_kernel(
        const float* __restrict__ attended,
        const float* __restrict__ W,
        const float* __restrict__ bias,
        const int* __restrict__ counts,
        const int* __restrict__ lists,
        float* __restrict__ out) {
    int inst = blockIdx.x / ATILES;
    int tile = blockIdx.x % ATILES;
    int cnt  = counts[inst];
    if (cnt == 0) return;                 // unused instance: skip W entirely

    int wid  = threadIdx.x >> 6;
    int lane = threadIdx.x & 63;
    int a0   = tile * 8 + wid * 2;
    int a1   = a0 + 1;
    bool v0  = a0 < NANS;
    bool v1  = a1 < NANS;

    const float* Wb = W + (size_t)inst * NANS * CC;

    float4 w0[8], w1[8];
    if (v0) {
        const float* wr = Wb + (size_t)a0 * CC + lane * 4;
        #pragma unroll
        for (int k = 0; k < 8; ++k) w0[k] = *(const float4*)(wr + k * 256);
    }
    if (v1) {
        const float* wr = Wb + (size_t)a1 * CC + lane * 4;
        #pragma unroll
        for (int k = 0; k < 8; ++k) w1[k] = *(const float4*)(wr + k * 256);
    }
    float b0 = v0 ? bias[inst * NANS + a0] : 0.f;
    float b1 = v1 ? bias[inst * NANS + a1] : 0.f;

    for (int j = 0; j < cnt; ++j) {
        int bj = lists[inst * BSZ + j];
        const float* ar = attended + (size_t)bj * CC + lane * 4;
        float acc0 = 0.f, acc1 = 0.f;
        #pragma unroll
        for (int k = 0; k < 8; ++k) {
            float4 a4 = *(const float4*)(ar + k * 256);
            if (v0) acc0 += a4.x * w0[k].x + a4.y * w0[k].y
                          + a4.z * w0[k].z + a4.w * w0[k].w;
            if (v1) acc1 += a4.x * w1[k].x + a4.y * w1[k].y
                          + a4.z * w1[k].z + a4.w * w1[k].w;
        }
        #pragma unroll
        for (int off = 32; off; off >>= 1) {
            acc0 += __shfl_xor(acc0, off, 64);
            acc1 += __shfl_xor(acc1, off, 64);
        }
        if (lane == 0) {
            if (v0) out[(size_t)bj * NANS + a0] = acc0 + b0;
            if (v1) out[(size_t)bj * NANS + a1] = acc1 + b1;
        }
    }
}

// ---------------------------------------------------------------------------
extern "C" void kernel_launch(void* const* d_in, const int* in_sizes, int n_in,
                              void* d_out, int out_size, void* d_ws, size_t ws_size,
                              hipStream_t stream) {
    const float* mask = (const float*)d_in[0];   // [128,1,14,14]
    const float* feat = (const float*)d_in[1];   // [128,2048,14,14]
    const int*   inst = (const int*)d_in[2];     // [128]
    const float* W    = (const float*)d_in[3];   // [32,1845,2048]
    const float* bias = (const float*)d_in[4];   // [32,1845]
    float*       out  = (float*)d_out;           // [128,1845]

    float* attended = (float*)d_ws;                          // 1 MB
    int*   counts   = (int*)((char*)d_ws + (size_t)BSZ * CC * sizeof(float));
    int*   lists    = counts + NDESC;                        // 32*128 ints

    group_kernel<<<1, BSZ, 0, stream>>>(inst, counts, lists);
    attend_kernel<<<(BSZ * CC) / 4, 256, 0, stream>>>(mask, feat, attended);
    gemm_kernel<<<NDESC * ATILES, 256, 0, stream>>>(attended, W, bias,
                                                    counts, lists, out);
}